// Round 12
// baseline (24375.163 us; speedup 1.0000x reference)
//
#include <hip/hip_runtime.h>
#include <math.h>

// ESN reservoir, persistent kernel, round 12.
// h_t = tanh(x_t Win^T + h_{t-1} W^T); out_t = h_t Wout^T + b
//
// r12 = r11 + ONE fix: explicit s_waitcnt(0) by ALL threads after the mailbox
// fan-out stores, BEFORE the barrier + flag store. r11 relied on __syncthreads
// draining vmcnt for stores -- not guaranteed; flag could outrun mailbox data
// (absmax 0.144 = occasional stale rows). r5/r8 used exactly this drain
// discipline and were race-free.
//
// Structure (r11): block = 64 rows x 2 batches (rg=blk&31, g=blk>>5).
//  - producer writes its 64-row strip into each of its 32 consumers' private
//    mailboxes (4 coalesced UC dwords/thread; distinct lines -> streams).
//  - consumer stages its OWN 8KB mailbox via global_load_lds UC: sole reader
//    of every line -> BW/latency-bound (~1us) instead of 32-reader contention.
//  - race-free parity double-buffer: writer touches parity p only after the
//    gate saw all 32 group flags >= t; a flag implies staging of p done.
//  - W fp32 from d_in (L2-resident, r9-proven); chunk-0 register prefetch
//    before the gate. h in f16 (absmax 0.0039). Spins bounded: never hangs.

#define RDIM   2048
#define BATCH  16
#define TSTEPS 2048
#define NIN    3
#define NOUT   3
#define NBLK   256
#define NTHR   512

#define MB_U32    (NBLK * 2048)             // one parity: 256 consumers x 8KB
#define OFF_FLAGS 0                          // 256 dwords
#define OFF_MB0   1024                       // parity 0
#define OFF_MB1   (1024 + MB_U32)            // parity 1
#define WS_USED   (1024 + 2 * MB_U32)
#define ZERO_U32  (1024 + MB_U32)            // flags + parity0 (parity1 fully overwritten)
#define SPIN_MAX  (1L << 20)

#define CPOL_SC0_SC1 0x11                    // UC: read at coherence point

typedef _Float16 half2v __attribute__((ext_vector_type(2)));
union HU { unsigned u; half2v h; };

__device__ __forceinline__ void load_lds16(const void* g, void* l) {
    __builtin_amdgcn_global_load_lds(
        (const __attribute__((address_space(1))) void*)g,
        (__attribute__((address_space(3))) void*)l, 16, 0, CPOL_SC0_SC1);
}

__device__ __forceinline__ unsigned sysld(const unsigned* p) {
    return __hip_atomic_load(p, __ATOMIC_RELAXED, __HIP_MEMORY_SCOPE_SYSTEM);
}
__device__ __forceinline__ void sysst(unsigned* p, unsigned v) {
    __hip_atomic_store(p, v, __ATOMIC_RELAXED, __HIP_MEMORY_SCOPE_SYSTEM);
}

__device__ __forceinline__ float f16lo(unsigned u) { HU c; c.u = u; return (float)c.h.x; }
__device__ __forceinline__ float f16hi(unsigned u) { HU c; c.u = u; return (float)c.h.y; }
__device__ __forceinline__ unsigned packf16(float a, float b) {
    HU c; c.h.x = (_Float16)a; c.h.y = (_Float16)b; return c.u;
}
__device__ __forceinline__ float f16s(unsigned short s) {
    union { unsigned short u; _Float16 h; } c; c.u = s; return (float)c.h;
}

extern "C" __global__ void __launch_bounds__(NTHR, 1) esn_persist(
    const float* __restrict__ W,       // [R,R] fp32 (d_in: L2-resident)
    const float* __restrict__ Win,     // [R,3]
    const float* __restrict__ x,       // [B,T,3]
    const float* __restrict__ Wout,    // [3,R]
    const float* __restrict__ bout,    // [3]
    unsigned* mb0,                     // mailbox parity 0: [g*32+rg_c][32][64]
    unsigned* mb1,                     // mailbox parity 1
    unsigned* flags,                   // [256]
    float* __restrict__ out)           // [B,T,3]
{
    __shared__ unsigned hs_dw[2048];            // 8 KB: dword r = (h[r][b0],h[r][b1])
    __shared__ float red[8][544];               // transpose-reduce scratch
    __shared__ float hblk[64][2];               // block's 64 rows x 2 batches

    const int tid  = threadIdx.x;
    const int lane = tid & 63;
    const int w    = tid >> 6;                  // wave 0..7
    const int blk  = blockIdx.x;
    const int rg   = blk & 31;                  // row-group: rows rg*64..+64
    const int g    = blk >> 5;                  // batch-group: batches g*2..+2
    const int rbase = rg * 64 + w * 8;          // wave's 8 rows
    const int b0    = g * 2;                    // block's first batch

    const float4* W4 = (const float4*)W;
    // lane's k-slice base within a 512-chunk: 8 consecutive k
    const int klane = (lane >> 3) * 64 + (lane & 7) * 8;

    for (int t = 0; t <= TSTEPS; ++t) {
        const unsigned* mbRd = (t & 1) ? mb1 : mb0;   // parity t&1 holds h_t
        unsigned*       mbWr = (t & 1) ? mb0 : mb1;
        const unsigned  tgt  = (unsigned)t;

        // ---- W chunk-0 prefetch (independent of gate/stage; L2-resident) ----
        float4 wq[8][2];
        if (t < TSTEPS) {
#pragma unroll
            for (int r = 0; r < 8; ++r) {
                const float4* Wp = W4 + (size_t)(rbase + r) * (RDIM / 4) + (klane >> 2);
                wq[r][0] = Wp[0];
                wq[r][1] = Wp[1];
            }
        }

        // ---- gate: all 32 producers of my group at version >= t ----
        if (t > 0 && w == 0) {
            long spins = 0;
            for (;;) {
                unsigned vv = (lane < 32) ? sysld(&flags[g * 32 + lane]) : tgt;
                if (__all((int)(vv >= tgt))) break;
                __builtin_amdgcn_s_sleep(2);
                if (++spins > SPIN_MAX) break;   // never hang
            }
        }
        __syncthreads();

        // ---- stage OWN mailbox (8 KB, sole reader of every line) ----
        {
            const unsigned* src = mbRd + (size_t)(g * 32 + rg) * 2048;
            const int gran = w * 64 + lane;              // 16B granule 0..511
            load_lds16(src + (size_t)gran * 4, hs_dw + (size_t)(w * 64) * 4);
        }
        __syncthreads();   // staging complete (drains vmcnt incl. W prefetch)

        if (t < TSTEPS) {
            // ---- recurrence: acc[r][b] over lane's k-slice ----
            float acc[8][2];
#pragma unroll
            for (int r = 0; r < 8; ++r) { acc[r][0] = 0.f; acc[r][1] = 0.f; }

            const uint4* h4 = (const uint4*)hs_dw;
#pragma unroll
            for (int c = 0; c < 4; ++c) {
                const int kb = c * 512 + klane;          // chunk k-base
                const int gi = kb >> 2;                  // granule = 4 rows
                uint4 q0 = h4[gi];                       // rows kb..kb+3, both b
                uint4 q1 = h4[gi + 1];                   // rows kb+4..kb+7
#pragma unroll
                for (int r = 0; r < 8; ++r) {
                    float4 w0, w1;
                    if (c == 0) { w0 = wq[r][0]; w1 = wq[r][1]; }
                    else {
                        const float4* Wp = W4 + (size_t)(rbase + r) * (RDIM / 4) + (kb >> 2);
                        w0 = Wp[0];
                        w1 = Wp[1];
                    }
                    acc[r][0] += w0.x * f16lo(q0.x) + w0.y * f16lo(q0.y)
                               + w0.z * f16lo(q0.z) + w0.w * f16lo(q0.w)
                               + w1.x * f16lo(q1.x) + w1.y * f16lo(q1.y)
                               + w1.z * f16lo(q1.z) + w1.w * f16lo(q1.w);
                    acc[r][1] += w0.x * f16hi(q0.x) + w0.y * f16hi(q0.y)
                               + w0.z * f16hi(q0.z) + w0.w * f16hi(q0.w)
                               + w1.x * f16hi(q1.x) + w1.y * f16hi(q1.y)
                               + w1.z * f16hi(q1.z) + w1.w * f16hi(q1.w);
                }
            }

            // ---- reduce: fold 32, swizzled transpose, sum 32 partials ----
            float v[16];
#pragma unroll
            for (int i = 0; i < 16; ++i) {
                float a = acc[i >> 1][i & 1];
                v[i] = a + __shfl_xor(a, 32, 64);
            }
            if (lane < 32) {
#pragma unroll
                for (int i = 0; i < 16; ++i)
                    red[w][lane * 17 + ((i + lane) & 15)] = v[i];
            }
            __syncthreads();
            if (lane < 16) {
                float s = 0.f;
#pragma unroll
                for (int l = 0; l < 32; ++l)
                    s += red[w][l * 17 + ((lane + l) & 15)];
                const int r   = lane >> 1;          // 0..7
                const int b   = lane & 1;
                const int row = rbase + r;
                const int bg  = b0 + b;
                float pre = s;
#pragma unroll
                for (int c = 0; c < NIN; ++c)
                    pre += Win[row * NIN + c] * x[((size_t)bg * TSTEPS + t) * NIN + c];
                hblk[w * 8 + r][b] = tanhf(pre);
            }
            __syncthreads();   // hblk complete

            // ---- mailbox fan-out: strip -> 32 consumers, coalesced UC ----
            {
                unsigned* base = mbWr + (size_t)g * 32 * 2048 + rg * 64;
#pragma unroll
                for (int s = 0; s < 4; ++s) {
                    const int d   = s * NTHR + tid;     // 0..2047
                    const int rgc = d >> 6;             // consumer row-group
                    const int j   = d & 63;             // row within strip
                    sysst(base + (size_t)rgc * 2048 + j,
                          packf16(hblk[j][0], hblk[j][1]));
                }
            }
            // THE r12 FIX: every thread drains its own mailbox stores to the
            // coherence point BEFORE the barrier; only then may tid 0 flag.
            // (__syncthreads alone does not order global stores.)
            __builtin_amdgcn_s_waitcnt(0);
            __syncthreads();
            if (tid == 0) sysst(&flags[g * 32 + rg], (unsigned)(t + 1));
        }

        // ---- projection of h_{t-1}-state (in hs) by rotating block ----
        if (t > 0 && rg == ((t - 1) & 31)) {
            const unsigned short* hsv = (const unsigned short*)hs_dw;
            const int o = t - 1;
            if (w < 6) {
                const int b = w / NOUT;             // 0..1
                const int k = w % NOUT;             // 0..2
                float a = 0.f;
#pragma unroll
                for (int j = 0; j < 32; ++j) {
                    const int r = j * 64 + lane;
                    a += f16s(hsv[2 * r + b]) * Wout[k * RDIM + r];
                }
#pragma unroll
                for (int off = 32; off >= 1; off >>= 1)
                    a += __shfl_xor(a, off, 64);
                if (lane == 0)
                    out[((size_t)(b0 + b) * TSTEPS + o) * NOUT + k] = a + bout[k];
            }
        }
    }
}

extern "C" void kernel_launch(void* const* d_in, const int* in_sizes, int n_in,
                              void* d_out, int out_size, void* d_ws, size_t ws_size,
                              hipStream_t stream) {
    const float* x    = (const float*)d_in[0];
    const float* Win  = (const float*)d_in[1];
    const float* W    = (const float*)d_in[2];
    const float* Wout = (const float*)d_in[3];
    const float* bout = (const float*)d_in[4];
    float* out = (float*)d_out;

    unsigned* wsu   = (unsigned*)d_ws;
    unsigned* flags = wsu + OFF_FLAGS;
    unsigned* mb0   = wsu + OFF_MB0;
    unsigned* mb1   = wsu + OFF_MB1;

    // zero flags + parity-0 mailbox (h0 = 0). parity-1 is fully overwritten
    // before any read (gate orders writers after readers' flags).
    hipMemsetAsync(d_ws, 0, (size_t)ZERO_U32 * sizeof(unsigned), stream);

    void* args[] = {(void*)&W, (void*)&Win, (void*)&x, (void*)&Wout, (void*)&bout,
                    (void*)&mb0, (void*)&mb1, (void*)&flags, (void*)&out};
    hipError_t e = hipLaunchCooperativeKernel((const void*)esn_persist,
                                              dim3(NBLK), dim3(NTHR),
                                              args, 0, stream);
    if (e != hipSuccess) {
        // Fallback: plain launch (256 blocks co-resident on 256 CUs; bounded
        // spins guarantee no hang regardless).
        esn_persist<<<dim3(NBLK), dim3(NTHR), 0, stream>>>(
            W, Win, x, Wout, bout, mb0, mb1, flags, out);
    }
}

// Round 13
// 10492.067 us; speedup vs baseline: 2.3232x; 2.3232x over previous
//
#include <hip/hip_runtime.h>
#include <math.h>

// ESN reservoir, persistent kernel, round 13.
// h_t = tanh(x_t Win^T + h_{t-1} W^T); out_t = h_t Wout^T + b
//
// Model closed by r5/r8/r12: d_ws is effectively fine-grained (uncacheable);
// exchange cost ~ bytes/0.57TB/s -> r8's 2MB/step layout is volume-optimal.
// r8 budget: gate+exchange 4.3 + max(W-L2 3.8, VALU 2.5) + 0.4 = 8.56us.
// Round 13 halves the W term: k<1024 W slice lives in 128KB dynamic LDS as
// packed f16x2 (converted once per launch), computed with v_dot2_f32_f16;
// k>=1024 streams fp32 W from d_in/L2 (r8-exact). Micro: one-hop gate with
// fast-poll, f16 h. Staging/reduce/strips/projection = r8-exact.
// All spins bounded: worst case wrong answer, never a hang.

#define RDIM   2048
#define BATCH  16
#define TSTEPS 2048
#define NIN    3
#define NOUT   3
#define NBLK   256
#define NTHR   512
#define KHALF  1024                          // k<KHALF from LDS-f16 W

#define HB_U32    ((BATCH * RDIM) / 2)       // 16384 dwords (packed f16x2)
#define OFF_H0    0
#define OFF_H1    (HB_U32)
#define OFF_FLAGS (2 * HB_U32)               // 256 dwords
#define WS_USED   (OFF_FLAGS + 256)
#define WLDS_DW   (64 * (KHALF / 2))         // 32768 dwords = 128 KB
#define SPIN_MAX  (1L << 20)

#define CPOL_SC0_SC1 0x11                    // UC: read at coherence point

typedef _Float16 half2v __attribute__((ext_vector_type(2)));
union HU { unsigned u; half2v h; };

__device__ __forceinline__ void load_lds16(const void* g, void* l) {
    __builtin_amdgcn_global_load_lds(
        (const __attribute__((address_space(1))) void*)g,
        (__attribute__((address_space(3))) void*)l, 16, 0, CPOL_SC0_SC1);
}

__device__ __forceinline__ unsigned sysld(const unsigned* p) {
    return __hip_atomic_load(p, __ATOMIC_RELAXED, __HIP_MEMORY_SCOPE_SYSTEM);
}
__device__ __forceinline__ void sysst(unsigned* p, unsigned v) {
    __hip_atomic_store(p, v, __ATOMIC_RELAXED, __HIP_MEMORY_SCOPE_SYSTEM);
}

__device__ __forceinline__ float f16lo(unsigned u) { HU c; c.u = u; return (float)c.h.x; }
__device__ __forceinline__ float f16hi(unsigned u) { HU c; c.u = u; return (float)c.h.y; }
__device__ __forceinline__ unsigned packf16(float a, float b) {
    HU c; c.h.x = (_Float16)a; c.h.y = (_Float16)b; return c.u;
}
__device__ __forceinline__ float f16s(unsigned short s) {
    union { unsigned short u; _Float16 h; } c; c.u = s; return (float)c.h;
}

// 8-element f16 dot: wq . hq + c, fp32 accumulate (v_dot2_f32_f16)
__device__ __forceinline__ float dot8(uint4 wq, uint4 hq, float c) {
#if __has_builtin(__builtin_amdgcn_fdot2)
    HU a, b;
    a.u = wq.x; b.u = hq.x; c = __builtin_amdgcn_fdot2(a.h, b.h, c, false);
    a.u = wq.y; b.u = hq.y; c = __builtin_amdgcn_fdot2(a.h, b.h, c, false);
    a.u = wq.z; b.u = hq.z; c = __builtin_amdgcn_fdot2(a.h, b.h, c, false);
    a.u = wq.w; b.u = hq.w; c = __builtin_amdgcn_fdot2(a.h, b.h, c, false);
#else
    c += f16lo(wq.x) * f16lo(hq.x) + f16hi(wq.x) * f16hi(hq.x);
    c += f16lo(wq.y) * f16lo(hq.y) + f16hi(wq.y) * f16hi(hq.y);
    c += f16lo(wq.z) * f16lo(hq.z) + f16hi(wq.z) * f16hi(hq.z);
    c += f16lo(wq.w) * f16lo(hq.w) + f16hi(wq.w) * f16hi(hq.w);
#endif
    return c;
}

extern "C" __global__ void __launch_bounds__(NTHR, 1) esn_persist(
    const float* __restrict__ W,       // [R,R] fp32 (d_in: L2-resident)
    const float* __restrict__ Win,     // [R,3]
    const float* __restrict__ x,       // [B,T,3]
    const float* __restrict__ Wout,    // [3,R]
    const float* __restrict__ bout,    // [3]
    unsigned* hb0,                     // [B][R/2] packed f16x2
    unsigned* hb1,
    unsigned* flags,                   // [256]
    float* __restrict__ out)           // [B,T,3]
{
    __shared__ unsigned hs_dw[2048];            // 8 KB: [2 batches][1024 dwords]
    __shared__ float red[8][544];               // transpose-reduce scratch
    __shared__ float hblk[64][2];               // 64 rows x 2 batches
    extern __shared__ unsigned wlds[];          // 128 KB: W[64 rows][k<1024] f16x2

    const int tid  = threadIdx.x;
    const int lane = tid & 63;
    const int w    = tid >> 6;                  // wave 0..7
    const int blk  = blockIdx.x;
    const int rg   = blk & 31;                  // rows rg*64..+64
    const int g    = blk >> 5;                  // batches g*2..+2
    const int rbase = rg * 64 + w * 8;          // wave's 8 rows
    const int b0    = g * 2;

    const float4* W4 = (const float4*)W;        // row stride 512 float4

    // ---- one-time: convert W rows, k<1024 -> LDS packed f16x2 ----
#pragma unroll
    for (int i = 0; i < WLDS_DW / NTHR; ++i) {  // 64 iters
        const int idx = i * NTHR + tid;         // r*512 + kk
        const int r   = idx >> 9;
        const int kk  = idx & 511;
        const float2 v = ((const float2*)(W + (size_t)(rg * 64 + r) * RDIM))[kk];
        wlds[idx] = packf16(v.x, v.y);
    }
    __syncthreads();

    for (int t = 0; t <= TSTEPS; ++t) {
        const unsigned* hprev = (t & 1) ? hb1 : hb0;
        unsigned*       hnext = (t & 1) ? hb0 : hb1;
        const unsigned  tgt   = (unsigned)t;

        // ---- one-hop gate: all 32 producers of my group at >= t ----
        if (t > 0 && w == 0) {
            long spins = 0;
            for (;;) {
                unsigned vv = (lane < 32) ? sysld(&flags[g * 32 + lane]) : tgt;
                if (__all((int)(vv >= tgt))) break;
                if (spins > 64) __builtin_amdgcn_s_sleep(2);  // fast-poll first
                if (++spins > SPIN_MAX) break;   // never hang
            }
        }
        __syncthreads();

        // ---- stage h[b0..b0+1][:] (8 KB) -> LDS, r8-exact ----
        {
            const int gran = w * 64 + lane;              // 16B granule 0..511
            load_lds16(hprev + (size_t)g * 2048 + (size_t)gran * 4,
                       (char*)hs_dw + (size_t)(w * 64) * 16);
        }
        __syncthreads();   // staging complete (drains vmcnt)

        if (t < TSTEPS) {
            float acc[8][2];
#pragma unroll
            for (int r = 0; r < 8; ++r) { acc[r][0] = 0.f; acc[r][1] = 0.f; }

            const uint4* h4 = (const uint4*)hs_dw;   // b0: 0..255, b1: 256..511

            // ---- k < 1024: W from LDS (f16), fdot2 ----
            {
                const uint4* w4p = (const uint4*)wlds;
                uint4 hA0 = h4[lane * 2];             // b0, k = lane*16..+16
                uint4 hA1 = h4[lane * 2 + 1];
                uint4 hB0 = h4[256 + lane * 2];       // b1
                uint4 hB1 = h4[256 + lane * 2 + 1];
#pragma unroll
                for (int rr = 0; rr < 8; ++rr) {
                    const int wb = (w * 8 + rr) * 128 + lane * 2;
                    uint4 w0 = w4p[wb];
                    uint4 w1 = w4p[wb + 1];
                    acc[rr][0] = dot8(w0, hA0, acc[rr][0]);
                    acc[rr][0] = dot8(w1, hA1, acc[rr][0]);
                    acc[rr][1] = dot8(w0, hB0, acc[rr][1]);
                    acc[rr][1] = dot8(w1, hB1, acc[rr][1]);
                }
            }

            // ---- k >= 1024: W fp32 from L2, r8-exact structure ----
#pragma unroll
            for (int c = 2; c < 4; ++c) {
                const int gr = c * 64 + lane;        // granule 128..255 (8 k)
                uint4 q0 = h4[gr];                   // batch b0
                uint4 q1 = h4[256 + gr];             // batch b0+1
                float a0 = f16lo(q0.x), a1 = f16hi(q0.x);
                float a2 = f16lo(q0.y), a3 = f16hi(q0.y);
                float a4 = f16lo(q0.z), a5 = f16hi(q0.z);
                float a6 = f16lo(q0.w), a7 = f16hi(q0.w);
                float c0 = f16lo(q1.x), c1 = f16hi(q1.x);
                float c2 = f16lo(q1.y), c3 = f16hi(q1.y);
                float c4 = f16lo(q1.z), c5 = f16hi(q1.z);
                float c6 = f16lo(q1.w), c7 = f16hi(q1.w);
#pragma unroll
                for (int rr = 0; rr < 8; ++rr) {
                    const float4* Wp = W4 + (size_t)(rbase + rr) * (RDIM / 4) + gr * 2;
                    float4 w0 = Wp[0];
                    float4 w1 = Wp[1];
                    acc[rr][0] += w0.x * a0 + w0.y * a1 + w0.z * a2 + w0.w * a3
                                + w1.x * a4 + w1.y * a5 + w1.z * a6 + w1.w * a7;
                    acc[rr][1] += w0.x * c0 + w0.y * c1 + w0.z * c2 + w0.w * c3
                                + w1.x * c4 + w1.y * c5 + w1.z * c6 + w1.w * c7;
                }
            }

            // ---- reduce: fold 32, swizzled transpose, sum 32 partials ----
            float v[16];
#pragma unroll
            for (int i = 0; i < 16; ++i) {
                float a = acc[i >> 1][i & 1];
                v[i] = a + __shfl_xor(a, 32, 64);
            }
            if (lane < 32) {
#pragma unroll
                for (int i = 0; i < 16; ++i)
                    red[w][lane * 17 + ((i + lane) & 15)] = v[i];
            }
            __syncthreads();
            if (lane < 16) {
                float s = 0.f;
#pragma unroll
                for (int l = 0; l < 32; ++l)
                    s += red[w][l * 17 + ((lane + l) & 15)];
                const int r   = lane >> 1;          // 0..7
                const int b   = lane & 1;
                const int row = rbase + r;
                const int bg  = b0 + b;
                float pre = s;
#pragma unroll
                for (int c = 0; c < NIN; ++c)
                    pre += Win[row * NIN + c] * x[((size_t)bg * TSTEPS + t) * NIN + c];
                hblk[w * 8 + r][b] = tanhf(pre);
            }
            __syncthreads();   // hblk complete

            // ---- write h_new strips (UC) + flag, r8-exact discipline ----
            if (w == 0) {
                const int b = lane >> 5;            // 0..1
                const int j = lane & 31;            // dword within 64-row strip
                sysst(&hnext[(size_t)(b0 + b) * (RDIM / 2) + rg * 32 + j],
                      packf16(hblk[2 * j][b], hblk[2 * j + 1][b]));
                __builtin_amdgcn_s_waitcnt(0);      // strips visible first
            }
            __syncthreads();
            if (tid == 0) sysst(&flags[g * 32 + rg], (unsigned)(t + 1));
        }

        // ---- projection of h_{t-1}-state (in hs) by rotating block ----
        if (t > 0 && rg == ((t - 1) & 31)) {
            const unsigned short* hsv = (const unsigned short*)hs_dw;
            const int o = t - 1;
            if (w < 6) {
                const int b = w / NOUT;             // 0..1
                const int k = w % NOUT;             // 0..2
                float a = 0.f;
#pragma unroll
                for (int j = 0; j < 32; ++j) {
                    const int r = j * 64 + lane;
                    a += f16s(hsv[b * RDIM + r]) * Wout[k * RDIM + r];
                }
#pragma unroll
                for (int off = 32; off >= 1; off >>= 1)
                    a += __shfl_xor(a, off, 64);
                if (lane == 0)
                    out[((size_t)(b0 + b) * TSTEPS + o) * NOUT + k] = a + bout[k];
            }
        }
    }
}

extern "C" void kernel_launch(void* const* d_in, const int* in_sizes, int n_in,
                              void* d_out, int out_size, void* d_ws, size_t ws_size,
                              hipStream_t stream) {
    const float* x    = (const float*)d_in[0];
    const float* Win  = (const float*)d_in[1];
    const float* W    = (const float*)d_in[2];
    const float* Wout = (const float*)d_in[3];
    const float* bout = (const float*)d_in[4];
    float* out = (float*)d_out;

    unsigned* wsu   = (unsigned*)d_ws;
    unsigned* hb0   = wsu + OFF_H0;
    unsigned* hb1   = wsu + OFF_H1;
    unsigned* flags = wsu + OFF_FLAGS;

    // zero h buffers + flags (~132 KB)
    hipMemsetAsync(d_ws, 0, (size_t)WS_USED * sizeof(unsigned), stream);

    // allow 128 KB dynamic LDS (idempotent; same work every call)
    hipFuncSetAttribute((const void*)esn_persist,
                        hipFuncAttributeMaxDynamicSharedMemorySize, 131072);

    void* args[] = {(void*)&W, (void*)&Win, (void*)&x, (void*)&Wout, (void*)&bout,
                    (void*)&hb0, (void*)&hb1, (void*)&flags, (void*)&out};
    hipError_t e = hipLaunchCooperativeKernel((const void*)esn_persist,
                                              dim3(NBLK), dim3(NTHR),
                                              args, 131072, stream);
    if (e != hipSuccess) {
        // Fallback: plain launch (256 blocks, 1/CU with 154KB LDS -> all
        // co-resident; bounded spins guarantee no hang regardless).
        esn_persist<<<dim3(NBLK), dim3(NTHR), 131072, stream>>>(
            W, Win, x, Wout, bout, hb0, hb1, flags, out);
    }
}